// Round 1
// baseline (742.643 us; speedup 1.0000x reference)
//
#include <hip/hip_runtime.h>
#include <hip/hip_bf16.h>

// Problem constants (from reference):
//   M=1e6, D=16 (values store), N=500000 neurons, K=8 fan-in.
// y_n = tanh(W_n @ sum_k values[idx[n,k]] + b_n)
//
// HBM-bound: W alone is 512 MB read-once. values (64 MB) fits in L3.

#define D_DIM 16
#define K_FAN 8
#define NEUR_PER_BLOCK 16   // 16 neurons x 16 lanes = 256 threads

__global__ __launch_bounds__(256)
void WeightedAtomLayer_55379308314866_kernel(
    const float* __restrict__ values,   // [M, 16]
    const int*   __restrict__ idx,      // [N, 8]  (harness materializes ints as int32)
    const float* __restrict__ W,        // [N, 16, 16]
    const float* __restrict__ b,        // [N, 16]
    float*       __restrict__ out,      // [N, 16]
    int N)
{
    __shared__ int   idx_sm[NEUR_PER_BLOCK][K_FAN];   // 128 ints
    __shared__ float s_sm[NEUR_PER_BLOCK][D_DIM];     // 256 floats

    const int t  = threadIdx.x;
    const int nl = t >> 4;     // local neuron 0..15
    const int i  = t & 15;     // row/element 0..15
    const int n0 = blockIdx.x * NEUR_PER_BLOCK;
    const int n  = n0 + nl;

    // Stage this block's 128 indices (coalesced int loads).
    if (t < NEUR_PER_BLOCK * K_FAN) {
        idx_sm[t >> 3][t & 7] = idx[n0 * K_FAN + t];
    }
    __syncthreads();

    // Gather + fan-in sum: lane i accumulates element i of each gathered row.
    // Each gathered row read is a 64B coalesced segment (16 lanes x 4B).
    float s = 0.0f;
    #pragma unroll
    for (int k = 0; k < K_FAN; ++k) {
        const long long row = (long long)idx_sm[nl][k];
        s += values[row * D_DIM + i];
    }
    s_sm[nl][i] = s;
    __syncthreads();

    // Per-neuron matvec: y_i = dot(W[n][i][:], s) + b[n][i].
    // Each thread reads its own contiguous 16-float W row as 4x float4;
    // across the wave every 64B line of W is fully consumed.
    const float4* Wv = (const float4*)(W + ((long long)n * (D_DIM * D_DIM)) + i * D_DIM);
    float acc = b[(long long)n * D_DIM + i];
    #pragma unroll
    for (int j4 = 0; j4 < 4; ++j4) {
        const float4 w = Wv[j4];
        acc += w.x * s_sm[nl][4 * j4 + 0];
        acc += w.y * s_sm[nl][4 * j4 + 1];
        acc += w.z * s_sm[nl][4 * j4 + 2];
        acc += w.w * s_sm[nl][4 * j4 + 3];
    }

    out[(long long)n * D_DIM + i] = tanhf(acc);
}

extern "C" void kernel_launch(void* const* d_in, const int* in_sizes, int n_in,
                              void* d_out, int out_size, void* d_ws, size_t ws_size,
                              hipStream_t stream) {
    const float* values = (const float*)d_in[0];   // [M,16] fp32
    const int*   idx    = (const int*)  d_in[1];   // [N,8]  int
    const float* W      = (const float*)d_in[2];   // [N,16,16] fp32
    const float* b      = (const float*)d_in[3];   // [N,16] fp32
    float*       out    = (float*)d_out;

    const int N = in_sizes[3] / D_DIM;             // 500000
    const int blocks = (N + NEUR_PER_BLOCK - 1) / NEUR_PER_BLOCK;  // 31250

    WeightedAtomLayer_55379308314866_kernel<<<blocks, 256, 0, stream>>>(
        values, idx, W, b, out, N);
}